// Round 9
// baseline (117.395 us; speedup 1.0000x reference)
//
#include <hip/hip_runtime.h>

// Problem constants (from reference setup_inputs): B=8, N=16384, K=64
#define BB 8
#define NN 16384
#define KK 64

#if __has_builtin(__builtin_amdgcn_exp2f)
#define EXP2(x) __builtin_amdgcn_exp2f(x)
#else
#define EXP2(x) exp2f(x)
#endif

typedef float v2f __attribute__((ext_vector_type(2)));

#if __has_builtin(__builtin_elementwise_fma)
#define FMA2(a, b, c) __builtin_elementwise_fma((a), (b), (c))
#else
static __device__ inline v2f FMA2(v2f a, v2f b, v2f c) {
    v2f r; r.x = fmaf(a.x, b.x, c.x); r.y = fmaf(a.y, b.y, c.y); return r;
}
#endif

#define LOG2E 1.44269504088896340736f
// exp(inv*dist) = exp2( CW*dot + CE*(n2+1) ), inv = -12.5, ||w||^2 == 1
#define CW (25.0f * LOG2E)
#define CE (-12.5f * LOG2E)

// ---------------------------------------------------------------------------
// Kernel 0: precompute scaled kernel directions as float4 AoS (one
// s_load_dwordx4 per (k,m) in the hot loop) AND zero the atomic accumulators
// (ws is re-poisoned 0xAA before every timed launch; stream order guarantees
// the zeroing lands before fkc_main's atomics).
// ---------------------------------------------------------------------------
__global__ __launch_bounds__(256) void fkc_prep(
    const float* __restrict__ walpha, const float* __restrict__ wbeta,
    float4* __restrict__ wq,             // [256] (wx,wy,wz,0)*CW
    float* __restrict__ gzero)           // [128] gsum|gss -> 0
{
    const int t = threadIdx.x;
    float a = walpha[t];
    float b = wbeta[t];
    float sa = __sinf(a);
    wq[t] = make_float4(CW * sa * __cosf(b),
                        CW * sa * __sinf(b),
                        CW * __cosf(a), 0.0f);
    if (t < 128) gzero[t] = 0.0f;
}

// ---------------------------------------------------------------------------
// Kernel 1: per-point feature compute (packed-FP32 dot products) + coalesced
// store + LDS-staged per-k (sum,sumsq) reduction + 2 atomicAdds per k.
// Grid = 2048 (512 pg x 4 k-quarters). feat kept at 16x reference scale
// (BN is scale-invariant). LDS stage padded 257 -> only 2-way bank aliasing
// (free per m136). NO butterfly shuffles (LDS-pipe hogs, see R6 post-mortem).
// ---------------------------------------------------------------------------
__global__ __launch_bounds__(256, 8) void fkc_main(
    const float* __restrict__ normals,   // (B,3,N)
    const int*   __restrict__ nidx,      // (B,N,3) int32
    const float4* __restrict__ wq,       // [256] wave-uniform -> s_load_dwordx4
    float* __restrict__ out,             // (B,K,N) feat (pre-BN, x16)
    float* __restrict__ gsum,            // [KK] zeroed by prep, atomic
    float* __restrict__ gss)             // [KK]
{
    __shared__ float fl[16][257];        // feats stage, 16.4 KB
    __shared__ float ps[16][17], pq[16][17];

    const int tid = threadIdx.x;
    const int pg = blockIdx.x >> 2;          // point group 0..511
    const int k0 = (blockIdx.x & 3) * 16;    // k quarter
    const int gid = pg * 256 + tid;
    const int b = gid >> 14;
    const int n = gid & (NN - 1);
    const float* nb = normals + b * 3 * NN;

    // Gather the 4 face points (center + 3 neighbors), all unit normals.
    float fx[4], fy[4], fz[4];
    fx[0] = nb[n];
    fy[0] = nb[NN + n];
    fz[0] = nb[2 * NN + n];
    const int ibase = (b * NN + n) * 3;
#pragma unroll
    for (int j = 0; j < 3; ++j) {
        int id = nidx[ibase + j];
        fx[j + 1] = nb[id];
        fy[j + 1] = nb[NN + id];
        fz[j + 1] = nb[2 * NN + id];
    }

    // Pack p-pairs for v_pk_fma_f32.
    v2f fx01 = {fx[0], fx[1]}, fx23 = {fx[2], fx[3]};
    v2f fy01 = {fy[0], fy[1]}, fy23 = {fy[2], fy[3]};
    v2f fz01 = {fz[0], fz[1]}, fz23 = {fz[2], fz[3]};
    v2f e01, e23;
    {
        v2f n2a = FMA2(fx01, fx01, FMA2(fy01, fy01, fz01 * fz01));
        v2f n2b = FMA2(fx23, fx23, FMA2(fy23, fy23, fz23 * fz23));
        e01 = CE * (n2a + 1.0f);
        e23 = CE * (n2b + 1.0f);
    }

    float* orow = out + (b * KK + k0) * NN + n;
#pragma unroll
    for (int kk = 0; kk < 16; ++kk) {
        v2f acc01 = {0.0f, 0.0f}, acc23 = {0.0f, 0.0f};
#pragma unroll
        for (int m = 0; m < 4; ++m) {
            float4 w = wq[((k0 + kk) << 2) + m];   // s_load_dwordx4
            v2f wx2 = {w.x, w.x}, wy2 = {w.y, w.y}, wz2 = {w.z, w.z};
            v2f a01 = FMA2(fz01, wz2, FMA2(fy01, wy2, FMA2(fx01, wx2, e01)));
            v2f a23 = FMA2(fz23, wz2, FMA2(fy23, wy2, FMA2(fx23, wx2, e23)));
            v2f x01 = {EXP2(a01.x), EXP2(a01.y)};
            v2f x23 = {EXP2(a23.x), EXP2(a23.y)};
            acc01 += x01;
            acc23 += x23;
        }
        v2f t2 = acc01 + acc23;
        float acc = t2.x + t2.y;
        orow[kk * NN] = acc;
        fl[kk][tid] = acc;
    }
    __syncthreads();

    // Column-sum the stage: thread (k = tid&15, part = tid>>4) sums 16 feats.
    {
        const int k = tid & 15;
        const int part = tid >> 4;
        float s = 0.0f, ss = 0.0f;
#pragma unroll
        for (int r = 0; r < 16; ++r) {
            float v = fl[k][part * 16 + r];
            s += v;
            ss = fmaf(v, v, ss);
        }
        ps[k][part] = s;
        pq[k][part] = ss;
    }
    __syncthreads();

    if (tid < 16) {
        float s = 0.0f;
#pragma unroll
        for (int r = 0; r < 16; ++r) s += ps[tid][r];
        atomicAdd(&gsum[k0 + tid], s);
    } else if (tid < 32) {
        const int kk = tid - 16;
        float ss = 0.0f;
#pragma unroll
        for (int r = 0; r < 16; ++r) ss += pq[kk][r];
        atomicAdd(&gss[k0 + kk], ss);
    }
}

// ---------------------------------------------------------------------------
// Kernel 2: BN + ReLU in place, 2x float4 per thread (512 f4 per block ->
// k uniform: 4096 f4 per (b,k) row, 8 blocks per row).
// ---------------------------------------------------------------------------
__global__ __launch_bounds__(256) void fkc_apply(
    float4* __restrict__ out4,
    const float* __restrict__ gsum,
    const float* __restrict__ gss,
    const float* __restrict__ gamma,
    const float* __restrict__ beta)
{
    const int tid = threadIdx.x;
    const int base = blockIdx.x * 512;
    const int k = (base >> 12) & (KK - 1);   // uniform within block

    const float invM = 1.0f / (float)(BB * NN);
    float mean = gsum[k] * invM;
    float var = fmaf(-mean, mean, gss[k] * invM);   // biased variance
    float sc = gamma[k] * rsqrtf(var + 1e-5f);
    float sh = fmaf(-mean, sc, beta[k]);

#pragma unroll
    for (int r = 0; r < 2; ++r) {
        const int i = base + r * 256 + tid;
        float4 v = out4[i];
        v.x = fmaxf(fmaf(v.x, sc, sh), 0.0f);
        v.y = fmaxf(fmaf(v.y, sc, sh), 0.0f);
        v.z = fmaxf(fmaf(v.z, sc, sh), 0.0f);
        v.w = fmaxf(fmaf(v.w, sc, sh), 0.0f);
        out4[i] = v;
    }
}

extern "C" void kernel_launch(void* const* d_in, const int* in_sizes, int n_in,
                              void* d_out, int out_size, void* d_ws, size_t ws_size,
                              hipStream_t stream) {
    const float* normals = (const float*)d_in[0];
    const int*   nidx    = (const int*)d_in[1];
    const float* walpha  = (const float*)d_in[2];
    const float* wbeta   = (const float*)d_in[3];
    const float* gamma   = (const float*)d_in[4];
    const float* beta    = (const float*)d_in[5];
    float* out = (float*)d_out;
    float* ws = (float*)d_ws;

    float* gsum = ws;            // [64]  (atomic accumulators, zeroed by prep)
    float* gss  = ws + 64;       // [64]
    float4* wq  = (float4*)(ws + 128);   // [256] float4 (16B-aligned: 512B off)

    fkc_prep<<<1, 256, 0, stream>>>(walpha, wbeta, wq, ws);
    fkc_main<<<2048, 256, 0, stream>>>(normals, nidx, wq, out, gsum, gss);
    fkc_apply<<<4096, 256, 0, stream>>>((float4*)out, gsum, gss, gamma, beta);
}

// Round 10
// 110.665 us; speedup vs baseline: 1.0608x; 1.0608x over previous
//
#include <hip/hip_runtime.h>

// Problem constants (from reference setup_inputs): B=8, N=16384, K=64
#define BB 8
#define NN 16384
#define KK 64

#if __has_builtin(__builtin_amdgcn_exp2f)
#define EXP2(x) __builtin_amdgcn_exp2f(x)
#else
#define EXP2(x) exp2f(x)
#endif

typedef float v2f __attribute__((ext_vector_type(2)));

#if __has_builtin(__builtin_elementwise_fma)
#define FMA2(a, b, c) __builtin_elementwise_fma((a), (b), (c))
#else
static __device__ inline v2f FMA2(v2f a, v2f b, v2f c) {
    v2f r; r.x = fmaf(a.x, b.x, c.x); r.y = fmaf(a.y, b.y, c.y); return r;
}
#endif

#define LOG2E 1.44269504088896340736f
// exp(inv*dist) = exp2( CW*dot + CE*(n2+1) ), inv = -12.5, ||w||^2 == 1
#define CW (25.0f * LOG2E)
#define CE (-12.5f * LOG2E)

// ---------------------------------------------------------------------------
// Kernel 0: precompute scaled kernel directions into global SoA so the hot
// loop reads them with wave-uniform addresses (scalar-load path, zero VALU).
// NOTE (R9 post-mortem): keep SoA float arrays — a float4 AoS load in the
// hot loop compiled to per-lane VMEM, not s_load, and cost ~6 us.
// ---------------------------------------------------------------------------
__global__ __launch_bounds__(256) void fkc_prep(
    const float* __restrict__ walpha, const float* __restrict__ wbeta,
    float* __restrict__ wx, float* __restrict__ wy, float* __restrict__ wz)
{
    const int t = threadIdx.x;
    float a = walpha[t];
    float b = wbeta[t];
    float sa = __sinf(a);
    wx[t] = CW * sa * __cosf(b);
    wy[t] = CW * sa * __sinf(b);
    wz[t] = CW * __cosf(a);
}

// ---------------------------------------------------------------------------
// Kernel 1: per-point feature compute (packed-FP32 dot products) + coalesced
// store + LDS-staged per-k (sum,sumsq) reduction + 2 atomicAdds per k.
// NO butterfly shuffles (they hammer the same LDS pipe: 192 ops vs ~36 here).
// Grid = 2048 (512 pg x 4 k-quarters). feat kept at 16x reference scale.
// LDS stage padded 257 -> only 2-way bank aliasing (free per m136).
// ---------------------------------------------------------------------------
__global__ __launch_bounds__(256, 8) void fkc_main(
    const float* __restrict__ normals,   // (B,3,N)
    const int*   __restrict__ nidx,      // (B,N,3) int32
    const float* __restrict__ wx, const float* __restrict__ wy,
    const float* __restrict__ wz,
    float* __restrict__ out,             // (B,K,N) feat (pre-BN, x16)
    float* __restrict__ gsum,            // [KK] zero-init'd, atomic
    float* __restrict__ gss)             // [KK]
{
    __shared__ float fl[16][257];        // feats stage, 16.4 KB
    __shared__ float ps[16][17], pq[16][17];

    const int tid = threadIdx.x;
    const int pg = blockIdx.x >> 2;          // point group 0..511
    const int k0 = (blockIdx.x & 3) * 16;    // k quarter
    const int gid = pg * 256 + tid;
    const int b = gid >> 14;
    const int n = gid & (NN - 1);
    const float* nb = normals + b * 3 * NN;

    // Gather the 4 face points (center + 3 neighbors), all unit normals.
    float fx[4], fy[4], fz[4];
    fx[0] = nb[n];
    fy[0] = nb[NN + n];
    fz[0] = nb[2 * NN + n];
    const int ibase = (b * NN + n) * 3;
#pragma unroll
    for (int j = 0; j < 3; ++j) {
        int id = nidx[ibase + j];
        fx[j + 1] = nb[id];
        fy[j + 1] = nb[NN + id];
        fz[j + 1] = nb[2 * NN + id];
    }

    // Pack p-pairs for v_pk_fma_f32.
    v2f fx01 = {fx[0], fx[1]}, fx23 = {fx[2], fx[3]};
    v2f fy01 = {fy[0], fy[1]}, fy23 = {fy[2], fy[3]};
    v2f fz01 = {fz[0], fz[1]}, fz23 = {fz[2], fz[3]};
    v2f e01, e23;
    {
        v2f n2a = FMA2(fx01, fx01, FMA2(fy01, fy01, fz01 * fz01));
        v2f n2b = FMA2(fx23, fx23, FMA2(fy23, fy23, fz23 * fz23));
        e01 = CE * (n2a + 1.0f);
        e23 = CE * (n2b + 1.0f);
    }

    float* orow = out + (b * KK + k0) * NN + n;
#pragma unroll
    for (int kk = 0; kk < 16; ++kk) {
        v2f acc01 = {0.0f, 0.0f}, acc23 = {0.0f, 0.0f};
#pragma unroll
        for (int m = 0; m < 4; ++m) {
            const int wi = ((k0 + kk) << 2) + m;   // wave-uniform -> s_load
            float wxv = wx[wi], wyv = wy[wi], wzv = wz[wi];
            v2f wx2 = {wxv, wxv}, wy2 = {wyv, wyv}, wz2 = {wzv, wzv};
            v2f a01 = FMA2(fz01, wz2, FMA2(fy01, wy2, FMA2(fx01, wx2, e01)));
            v2f a23 = FMA2(fz23, wz2, FMA2(fy23, wy2, FMA2(fx23, wx2, e23)));
            v2f x01 = {EXP2(a01.x), EXP2(a01.y)};
            v2f x23 = {EXP2(a23.x), EXP2(a23.y)};
            acc01 += x01;
            acc23 += x23;
        }
        v2f t2 = acc01 + acc23;
        float acc = t2.x + t2.y;
        orow[kk * NN] = acc;
        fl[kk][tid] = acc;
    }
    __syncthreads();

    // Column-sum the stage: thread (k = tid&15, part = tid>>4) sums 16 feats.
    {
        const int k = tid & 15;
        const int part = tid >> 4;
        float s = 0.0f, ss = 0.0f;
#pragma unroll
        for (int r = 0; r < 16; ++r) {
            float v = fl[k][part * 16 + r];
            s += v;
            ss = fmaf(v, v, ss);
        }
        ps[k][part] = s;
        pq[k][part] = ss;
    }
    __syncthreads();

    if (tid < 16) {
        float s = 0.0f;
#pragma unroll
        for (int r = 0; r < 16; ++r) s += ps[tid][r];
        atomicAdd(&gsum[k0 + tid], s);
    } else if (tid < 32) {
        const int kk = tid - 16;
        float ss = 0.0f;
#pragma unroll
        for (int r = 0; r < 16; ++r) ss += pq[kk][r];
        atomicAdd(&gss[k0 + kk], ss);
    }
}

// ---------------------------------------------------------------------------
// Kernel 2: BN + ReLU in place, float4. k uniform per block -> gsum/gss/
// gamma/beta all scalar loads; mean/var recomputed per block (trivial).
// (R9 post-mortem: keep 1 float4/thread, 8192 blocks — more latency hiding.)
// ---------------------------------------------------------------------------
__global__ __launch_bounds__(256) void fkc_apply(
    float4* __restrict__ out4,
    const float* __restrict__ gsum,
    const float* __restrict__ gss,
    const float* __restrict__ gamma,
    const float* __restrict__ beta)
{
    const int i = blockIdx.x * 256 + threadIdx.x;
    const int k = (i >> 12) & (KK - 1);      // uniform within block

    const float invM = 1.0f / (float)(BB * NN);
    float mean = gsum[k] * invM;
    float var = fmaf(-mean, mean, gss[k] * invM);   // biased variance
    float sc = gamma[k] * rsqrtf(var + 1e-5f);
    float sh = fmaf(-mean, sc, beta[k]);

    float4 v = out4[i];
    v.x = fmaxf(fmaf(v.x, sc, sh), 0.0f);
    v.y = fmaxf(fmaf(v.y, sc, sh), 0.0f);
    v.z = fmaxf(fmaf(v.z, sc, sh), 0.0f);
    v.w = fmaxf(fmaf(v.w, sc, sh), 0.0f);
    out4[i] = v;
}

extern "C" void kernel_launch(void* const* d_in, const int* in_sizes, int n_in,
                              void* d_out, int out_size, void* d_ws, size_t ws_size,
                              hipStream_t stream) {
    const float* normals = (const float*)d_in[0];
    const int*   nidx    = (const int*)d_in[1];
    const float* walpha  = (const float*)d_in[2];
    const float* wbeta   = (const float*)d_in[3];
    const float* gamma   = (const float*)d_in[4];
    const float* beta    = (const float*)d_in[5];
    float* out = (float*)d_out;
    float* ws = (float*)d_ws;

    float* gsum = ws;            // [64]  (atomic accumulators)
    float* gss  = ws + 64;       // [64]
    float* wxb  = ws + 128;      // [256]
    float* wyb  = ws + 384;      // [256]
    float* wzb  = ws + 640;      // [256]

    // ws is re-poisoned 0xAA before every timed launch -> zero the atomics.
    hipMemsetAsync(ws, 0, 128 * sizeof(float), stream);

    fkc_prep<<<1, 256, 0, stream>>>(walpha, wbeta, wxb, wyb, wzb);
    fkc_main<<<2048, 256, 0, stream>>>(normals, nidx, wxb, wyb, wzb,
                                       out, gsum, gss);
    fkc_apply<<<8192, 256, 0, stream>>>((float4*)out, gsum, gss, gamma, beta);
}